// Round 1
// baseline (5232.090 us; speedup 1.0000x reference)
//
#include <hip/hip_runtime.h>
#include <stdint.h>

// Problem constants
#define T_   512
#define B_   64
#define DIN  1024
#define HID  512
#define G3   1536     // 3*HID
#define NC   3072     // both dirs of gates
#define MROWS 32768   // T_*B_

typedef __bf16 bf16;
typedef __bf16 bf16x8 __attribute__((ext_vector_type(8)));
typedef float  f32x4  __attribute__((ext_vector_type(4)));

#define GLOBAL_AS __attribute__((address_space(1)))
#define LDS_AS    __attribute__((address_space(3)))

__device__ __forceinline__ uint16_t f2bf_bits(float x){
  union{float f; uint32_t u;} v; v.f = x;
  uint32_t u = v.u;
  u += 0x7FFFu + ((u >> 16) & 1u);   // round-to-nearest-even
  return (uint16_t)(u >> 16);
}
__device__ __forceinline__ float bf2f_bits(uint16_t h){
  union{uint32_t u; float f;} v; v.u = ((uint32_t)h) << 16;
  return v.f;
}

// ---------------------------------------------------------------- converts
__global__ void k_conv_emb(const float* __restrict__ src, uint16_t* __restrict__ dst, long n8){
  long i = (long)blockIdx.x*blockDim.x + threadIdx.x;
  if(i >= n8) return;
  const float4* s = (const float4*)src;
  float4 a = s[i*2], b = s[i*2+1];
  uint32_t p0 = (uint32_t)f2bf_bits(a.x) | ((uint32_t)f2bf_bits(a.y) << 16);
  uint32_t p1 = (uint32_t)f2bf_bits(a.z) | ((uint32_t)f2bf_bits(a.w) << 16);
  uint32_t p2 = (uint32_t)f2bf_bits(b.x) | ((uint32_t)f2bf_bits(b.y) << 16);
  uint32_t p3 = (uint32_t)f2bf_bits(b.z) | ((uint32_t)f2bf_bits(b.w) << 16);
  ((uint4*)dst)[i] = make_uint4(p0,p1,p2,p3);
}

__global__ void k_conv_wcat(const float* __restrict__ wf, const float* __restrict__ wb, uint16_t* __restrict__ dst, int n){
  int i = blockIdx.x*256 + threadIdx.x;
  if(i >= n) return;
  float v = (i < G3*DIN) ? wf[i] : wb[i - G3*DIN];
  dst[i] = f2bf_bits(v);
}

__global__ void k_conv_awt(const float* __restrict__ aw, uint16_t* __restrict__ dst, int n){
  int i = blockIdx.x*256 + threadIdx.x;
  if(i >= n) return;
  int e = i >> 10, d = i & 1023;
  dst[i] = f2bf_bits(aw[d*1024 + e]);   // transpose: awT[e][d]
}

// ---------------------------------------------------------------- GEMM: xp = emb @ Wcat^T + bias  (bf16 out)
// A: MROWS x 1024 bf16 (row-major, K-contig). Bw: 3072 x 1024 bf16 (row-major = B^T, K-contig).
__launch_bounds__(256)
__global__ void k_gemm_xp(const uint16_t* __restrict__ A, const uint16_t* __restrict__ Bw,
                          const float* __restrict__ bihf, const float* __restrict__ bihb,
                          uint16_t* __restrict__ C)
{
  __shared__ uint16_t lA[2][128*32];
  __shared__ uint16_t lB[2][128*32];
  const int K = 1024;
  int bn = blockIdx.x, bm = blockIdx.y;
  int tid = threadIdx.x;
  int lane = tid & 63, wid = tid >> 6;
  int wm = wid >> 1, wn = wid & 1;
  int rowBase = bm*128, colBase = bn*128;
  int rg = lane >> 4, rr = lane & 15;

  auto stage = [&](int buf, int kt){
    #pragma unroll
    for(int i=0;i<2;i++){
      int e = (i*256 + tid)*8;
      int r = e >> 5, c = e & 31;
      __builtin_amdgcn_global_load_lds((const GLOBAL_AS void*)(A + (size_t)(rowBase + r)*K + kt*32 + c),
                                       (LDS_AS void*)&lA[buf][e], 16, 0, 0);
    }
    #pragma unroll
    for(int i=0;i<2;i++){
      int e = (i*256 + tid)*8;
      int r = e >> 5, c = e & 31;
      __builtin_amdgcn_global_load_lds((const GLOBAL_AS void*)(Bw + (size_t)(colBase + r)*K + kt*32 + c),
                                       (LDS_AS void*)&lB[buf][e], 16, 0, 0);
    }
  };

  f32x4 acc[4][4];
  #pragma unroll
  for(int mi=0;mi<4;mi++)
    #pragma unroll
    for(int ni=0;ni<4;ni++) acc[mi][ni] = (f32x4){0.f,0.f,0.f,0.f};

  stage(0, 0);
  __syncthreads();
  for(int kt=0; kt<32; kt++){
    int buf = kt & 1;
    if(kt+1 < 32) stage(buf^1, kt+1);
    bf16x8 af[4], bfv[4];
    #pragma unroll
    for(int mi=0;mi<4;mi++)
      af[mi] = *(const bf16x8*)&lA[buf][(wm*64 + mi*16 + rr)*32 + rg*8];
    #pragma unroll
    for(int ni=0;ni<4;ni++)
      bfv[ni] = *(const bf16x8*)&lB[buf][(wn*64 + ni*16 + rr)*32 + rg*8];
    #pragma unroll
    for(int mi=0;mi<4;mi++)
      #pragma unroll
      for(int ni=0;ni<4;ni++)
        acc[mi][ni] = __builtin_amdgcn_mfma_f32_16x16x32_bf16(af[mi], bfv[ni], acc[mi][ni], 0,0,0);
    __syncthreads();
  }

  #pragma unroll
  for(int ni=0;ni<4;ni++){
    int col = colBase + wn*64 + ni*16 + rr;
    float bv = (col < G3) ? bihf[col] : bihb[col - G3];
    #pragma unroll
    for(int mi=0;mi<4;mi++){
      #pragma unroll
      for(int r=0;r<4;r++){
        int row = rowBase + wm*64 + mi*16 + rg*4 + r;
        C[(size_t)row*NC + col] = f2bf_bits(acc[mi][ni][r] + bv);
      }
    }
  }
}

// ---------------------------------------------------------------- GEMM: attention, fused tanh + ctx_w dot
__launch_bounds__(256)
__global__ void k_gemm_att(const uint16_t* __restrict__ A, const uint16_t* __restrict__ Bw,
                           const float* __restrict__ attn_b, const float* __restrict__ ctx_w,
                           float* __restrict__ scores_raw)
{
  __shared__ uint16_t lA[2][128*32];
  __shared__ uint16_t lB[2][128*32];
  const int K = 1024;
  int bn = blockIdx.x, bm = blockIdx.y;
  int tid = threadIdx.x;
  int lane = tid & 63, wid = tid >> 6;
  int wm = wid >> 1, wn = wid & 1;
  int rowBase = bm*128, colBase = bn*128;
  int rg = lane >> 4, rr = lane & 15;

  auto stage = [&](int buf, int kt){
    #pragma unroll
    for(int i=0;i<2;i++){
      int e = (i*256 + tid)*8;
      int r = e >> 5, c = e & 31;
      __builtin_amdgcn_global_load_lds((const GLOBAL_AS void*)(A + (size_t)(rowBase + r)*K + kt*32 + c),
                                       (LDS_AS void*)&lA[buf][e], 16, 0, 0);
    }
    #pragma unroll
    for(int i=0;i<2;i++){
      int e = (i*256 + tid)*8;
      int r = e >> 5, c = e & 31;
      __builtin_amdgcn_global_load_lds((const GLOBAL_AS void*)(Bw + (size_t)(colBase + r)*K + kt*32 + c),
                                       (LDS_AS void*)&lB[buf][e], 16, 0, 0);
    }
  };

  f32x4 acc[4][4];
  #pragma unroll
  for(int mi=0;mi<4;mi++)
    #pragma unroll
    for(int ni=0;ni<4;ni++) acc[mi][ni] = (f32x4){0.f,0.f,0.f,0.f};

  stage(0, 0);
  __syncthreads();
  for(int kt=0; kt<32; kt++){
    int buf = kt & 1;
    if(kt+1 < 32) stage(buf^1, kt+1);
    bf16x8 af[4], bfv[4];
    #pragma unroll
    for(int mi=0;mi<4;mi++)
      af[mi] = *(const bf16x8*)&lA[buf][(wm*64 + mi*16 + rr)*32 + rg*8];
    #pragma unroll
    for(int ni=0;ni<4;ni++)
      bfv[ni] = *(const bf16x8*)&lB[buf][(wn*64 + ni*16 + rr)*32 + rg*8];
    #pragma unroll
    for(int mi=0;mi<4;mi++)
      #pragma unroll
      for(int ni=0;ni<4;ni++)
        acc[mi][ni] = __builtin_amdgcn_mfma_f32_16x16x32_bf16(af[mi], bfv[ni], acc[mi][ni], 0,0,0);
    __syncthreads();
  }

  // epilogue: part[row] += sum_cols tanh(acc + attn_b[col]) * ctx_w[col]
  float ab[4], cw[4];
  #pragma unroll
  for(int ni=0;ni<4;ni++){
    int col = colBase + wn*64 + ni*16 + rr;
    ab[ni] = attn_b[col];
    cw[ni] = ctx_w[col];
  }
  #pragma unroll
  for(int mi=0;mi<4;mi++){
    #pragma unroll
    for(int r=0;r<4;r++){
      float part = 0.f;
      #pragma unroll
      for(int ni=0;ni<4;ni++) part += tanhf(acc[mi][ni][r] + ab[ni]) * cw[ni];
      #pragma unroll
      for(int off=1; off<16; off<<=1) part += __shfl_xor(part, off);
      if(rr == 0){
        int row = rowBase + wm*64 + mi*16 + rg*4 + r;
        atomicAdd(&scores_raw[row], part);
      }
    }
  }
}

// ---------------------------------------------------------------- recurrence (persistent, spin-synced)
// 8 chains = {dir(2) x batch-group(4, M=16)}; 16 WGs/chain; WG owns 32 h-cols (96 gh-cols).
__launch_bounds__(384, 1)
__global__ void k_recur(const uint16_t* __restrict__ xp,
                        const float* __restrict__ whhf, const float* __restrict__ whhb,
                        const float* __restrict__ bhhf, const float* __restrict__ bhhb,
                        uint16_t* __restrict__ h_pub, unsigned* __restrict__ ctr,
                        uint16_t* __restrict__ f_out)
{
  __shared__ uint16_t wl[96*520];   // w_hh slice, bf16, padded stride
  __shared__ uint16_t hl[16*520];   // published h (bf16), padded stride
  __shared__ float    ghl[96*17];   // gh exchange (col-major, padded)
  __shared__ float    hown[16*32];  // fp32 master h slice
  __shared__ float    bhl[96];

  int bid = blockIdx.x;
  int chain = bid & 7;          // co-XCD under round-robin dispatch (perf only)
  int member = bid >> 3;        // 0..15
  int dir = chain & 1;
  int bg  = chain >> 1;         // 0..3
  int jbase = member * 32;
  int tid = threadIdx.x;
  int lane = tid & 63, wid = tid >> 6;   // 6 waves
  int rg = lane >> 4, rr = lane & 15;

  const float* whh = dir ? whhb : whhf;
  const float* bhh = dir ? bhhb : bhhf;

  for(int i = tid; i < 96*512; i += 384){
    int row = i >> 9, k = i & 511;
    int g = row >> 5, j = row & 31;
    wl[row*520 + k] = f2bf_bits(whh[(size_t)(g*512 + jbase + j)*512 + k]);
  }
  for(int i = tid; i < 96; i += 384){
    int g = i >> 5, j = i & 31;
    bhl[i] = bhh[g*512 + jbase + j];
  }
  for(int i = tid; i < 16*520; i += 384) hl[i] = 0;
  for(int i = tid; i < 512;    i += 384) hown[i] = 0.f;
  __syncthreads();

  uint16_t* hp    = h_pub + (size_t)chain * (2*16*512);
  unsigned* myctr = ctr + chain*32;

  for(int t = 0; t < 512; t++){
    int trow = dir ? (511 - t) : t;

    // prefetch xp for this step (independent of the barrier)
    float xpv[2][3];
    if(tid < 256){
      #pragma unroll
      for(int e2=0; e2<2; e2++){
        int e = tid + e2*256;
        int m = e >> 5, j = e & 31;
        size_t rowoff = (size_t)(trow*64 + bg*16 + m)*NC + dir*G3;
        #pragma unroll
        for(int g=0; g<3; g++)
          xpv[e2][g] = bf2f_bits(xp[rowoff + g*512 + jbase + j]);
      }
    }

    if(t > 0){
      if(tid == 0){
        while(__hip_atomic_load(myctr, __ATOMIC_ACQUIRE, __HIP_MEMORY_SCOPE_AGENT) < (unsigned)(16*t))
          __builtin_amdgcn_s_sleep(2);
      }
      __syncthreads();
      const uint16_t* hsrc = hp + ((t-1)&1)*(16*512);
      for(int c = tid; c < 1024; c += 384){
        int m = c >> 6, kc = (c & 63)*8;
        *(bf16x8*)&hl[m*520 + kc] = *(const bf16x8*)&hsrc[m*512 + kc];
      }
      __syncthreads();
    }

    // gh = h @ w_slice^T  : wave `wid` computes 16x16 tile (16 batch rows x 16 gh cols)
    f32x4 acc = (f32x4){0.f,0.f,0.f,0.f};
    if(t > 0){
      #pragma unroll
      for(int ks = 0; ks < 16; ks++){
        bf16x8 a = *(const bf16x8*)&hl[rr*520 + ks*32 + rg*8];
        bf16x8 b = *(const bf16x8*)&wl[(wid*16 + rr)*520 + ks*32 + rg*8];
        acc = __builtin_amdgcn_mfma_f32_16x16x32_bf16(a, b, acc, 0,0,0);
      }
    }
    #pragma unroll
    for(int r=0;r<4;r++) ghl[(wid*16 + rr)*17 + rg*4 + r] = acc[r];
    __syncthreads();

    // gates (first 4 waves, 2 elems each)
    if(tid < 256){
      #pragma unroll
      for(int e2=0; e2<2; e2++){
        int e = tid + e2*256;
        int m = e >> 5, j = e & 31;
        float ghr = ghl[(j)*17      + m] + bhl[j];
        float ghz = ghl[(32+j)*17   + m] + bhl[32+j];
        float ghn = ghl[(64+j)*17   + m] + bhl[64+j];
        float rv = 1.f/(1.f + __expf(-(xpv[e2][0] + ghr)));
        float zv = 1.f/(1.f + __expf(-(xpv[e2][1] + ghz)));
        float nv = tanhf(xpv[e2][2] + rv*ghn);
        float hprev = hown[m*32 + j];
        float hnew = (1.f - zv)*nv + zv*hprev;
        hown[m*32 + j] = hnew;
        uint16_t hb = f2bf_bits(hnew);
        hp[(t&1)*(16*512) + m*512 + jbase + j] = hb;
        f_out[(size_t)(trow*64 + bg*16 + m)*1024 + dir*512 + jbase + j] = hb;
      }
    }
    __syncthreads();
    if(tid == 0){
      __threadfence();
      __hip_atomic_fetch_add(myctr, 1u, __ATOMIC_RELEASE, __HIP_MEMORY_SCOPE_AGENT);
    }
  }
}

// ---------------------------------------------------------------- softmax over T per batch
__global__ void k_softmax(const float* __restrict__ scores_raw, float* __restrict__ wsm){
  __shared__ float sv[512];
  __shared__ float red[8];
  int b = blockIdx.x;
  int tid = threadIdx.x;
  float mymax = -1e30f;
  for(int t = tid; t < 512; t += 256){
    float s = tanhf(scores_raw[t*64 + b]);
    sv[t] = s;
    mymax = fmaxf(mymax, s);
  }
  #pragma unroll
  for(int off=1; off<64; off<<=1) mymax = fmaxf(mymax, __shfl_xor(mymax, off));
  if((tid&63)==0) red[tid>>6] = mymax;
  __syncthreads();
  float bmax = fmaxf(fmaxf(red[0],red[1]), fmaxf(red[2],red[3]));
  __syncthreads();
  float mysum = 0.f;
  for(int t = tid; t < 512; t += 256){
    float e = __expf(sv[t] - bmax);
    sv[t] = e;
    mysum += e;
  }
  #pragma unroll
  for(int off=1; off<64; off<<=1) mysum += __shfl_xor(mysum, off);
  if((tid&63)==0) red[tid>>6] = mysum;
  __syncthreads();
  float inv = 1.f/(red[0]+red[1]+red[2]+red[3]);
  for(int t = tid; t < 512; t += 256) wsm[b*512 + t] = sv[t]*inv;
}

// ---------------------------------------------------------------- ctx[b,d] = sum_t w[b,t] f[t,b,d]
__global__ void k_ctx(const uint16_t* __restrict__ f_out, const float* __restrict__ wsm, float* __restrict__ ctx){
  __shared__ float wloc[512];
  int b = blockIdx.x >> 2, chunk = blockIdx.x & 3;
  int tid = threadIdx.x;
  for(int t = tid; t < 512; t += 256) wloc[t] = wsm[b*512 + t];
  __syncthreads();
  int d = chunk*256 + tid;
  float acc = 0.f;
  #pragma unroll 8
  for(int t = 0; t < 512; t++)
    acc += wloc[t] * bf2f_bits(f_out[(size_t)(t*64 + b)*1024 + d]);
  ctx[b*1024 + d] = acc;
}

// ---------------------------------------------------------------- classifier
__global__ void k_cls1(const float* __restrict__ ctx, const float* __restrict__ w1,
                       const float* __restrict__ b1, float* __restrict__ hid){
  int idx = blockIdx.x*256 + threadIdx.x;   // 32768
  int b = idx >> 9, h = idx & 511;
  float acc = b1[h];
  for(int d = 0; d < 1024; d++) acc += ctx[b*1024 + d] * w1[d*512 + h];
  hid[idx] = fmaxf(acc, 0.f);
}

__global__ void k_cls2(const float* __restrict__ hid, const float* __restrict__ w2,
                       const float* __restrict__ b2, float* __restrict__ out){
  int idx = threadIdx.x;   // 640
  if(idx >= 640) return;
  int b = idx / 10, o = idx % 10;
  float acc = b2[o];
  for(int h = 0; h < 512; h++) acc += hid[b*512 + h] * w2[h*10 + o];
  out[idx] = acc;
}

// ---------------------------------------------------------------- launch
extern "C" void kernel_launch(void* const* d_in, const int* in_sizes, int n_in,
                              void* d_out, int out_size, void* d_ws, size_t ws_size,
                              hipStream_t stream)
{
  const float* emb    = (const float*)d_in[1];
  const float* w_ih_f = (const float*)d_in[2];
  const float* w_hh_f = (const float*)d_in[3];
  const float* b_ih_f = (const float*)d_in[4];
  const float* b_hh_f = (const float*)d_in[5];
  const float* w_ih_b = (const float*)d_in[6];
  const float* w_hh_b = (const float*)d_in[7];
  const float* b_ih_b = (const float*)d_in[8];
  const float* b_hh_b = (const float*)d_in[9];
  const float* attn_w = (const float*)d_in[10];
  const float* attn_b = (const float*)d_in[11];
  const float* ctx_w  = (const float*)d_in[12];
  const float* cls_w1 = (const float*)d_in[13];
  const float* cls_b1 = (const float*)d_in[14];
  const float* cls_w2 = (const float*)d_in[15];
  const float* cls_b2 = (const float*)d_in[16];
  float* out = (float*)d_out;

  char* ws = (char*)d_ws;
  size_t off = 0;
  auto alloc = [&](size_t bytes){ void* p = ws + off; off += (bytes + 255) & ~(size_t)255; return p; };
  uint16_t* femb = (uint16_t*)alloc((size_t)MROWS*DIN*2);      // emb bf16, later overlaid by f_out
  uint16_t* wcat = (uint16_t*)alloc((size_t)NC*DIN*2);
  uint16_t* xp   = (uint16_t*)alloc((size_t)MROWS*NC*2);
  uint16_t* awT  = (uint16_t*)alloc((size_t)1024*1024*2);
  uint16_t* hpub = (uint16_t*)alloc((size_t)8*2*16*512*2);
  unsigned* ctr  = (unsigned*)alloc(4096);
  float* scraw   = (float*)alloc((size_t)MROWS*4);
  float* wsm     = (float*)alloc((size_t)B_*T_*4);
  float* ctx     = (float*)alloc((size_t)B_*1024*4);
  float* hid     = (float*)alloc((size_t)B_*512*4);

  hipMemsetAsync(ctr, 0, 4096, stream);
  hipMemsetAsync(scraw, 0, (size_t)MROWS*4, stream);

  k_conv_emb<<<16384, 256, 0, stream>>>(emb, femb, (long)MROWS*DIN/8);
  k_conv_wcat<<<12288, 256, 0, stream>>>(w_ih_f, w_ih_b, wcat, NC*DIN);
  k_conv_awt<<<4096, 256, 0, stream>>>(attn_w, awT, 1024*1024);

  k_gemm_xp<<<dim3(24,256), 256, 0, stream>>>(femb, wcat, b_ih_f, b_ih_b, xp);

  k_recur<<<128, 384, 0, stream>>>(xp, w_hh_f, w_hh_b, b_hh_f, b_hh_b, hpub, ctr, femb /* = f_out */);

  k_gemm_att<<<dim3(8,256), 256, 0, stream>>>(femb, awT, attn_b, ctx_w, scraw);
  k_softmax<<<64, 256, 0, stream>>>(scraw, wsm);
  k_ctx<<<256, 256, 0, stream>>>(femb, wsm, ctx);
  k_cls1<<<128, 256, 0, stream>>>(ctx, cls_w1, cls_b1, hid);
  k_cls2<<<1, 640, 0, stream>>>(hid, cls_w2, cls_b2, out);
}